// Round 1
// baseline (350.935 us; speedup 1.0000x reference)
//
#include <hip/hip_runtime.h>
#include <math.h>

#define N 1024
#define E 32
#define L 8

// ---------------- kernel 1: query + output tail ----------------
// blocks 0..31: query[e] = b_c[e] + dot(c_i, w_c[e,:])
// block 32: d_out tail = stack_ptr (8) + zeros (1024)
__global__ __launch_bounds__(256) void k_query_tail(
    const float* __restrict__ c_i, const float* __restrict__ w_c,
    const float* __restrict__ b_c, const float* __restrict__ ptr,
    float* __restrict__ query, float* __restrict__ out_tail) {
  int b = blockIdx.x;
  if (b < 32) {
    int e = b;
    float s = 0.f;
    for (int h = threadIdx.x; h < N; h += 256)
      s += c_i[h] * w_c[e * N + h];
    #pragma unroll
    for (int off = 32; off > 0; off >>= 1)
      s += __shfl_down(s, off, 64);
    __shared__ float red[4];
    if ((threadIdx.x & 63) == 0) red[threadIdx.x >> 6] = s;
    __syncthreads();
    if (threadIdx.x == 0)
      query[e] = red[0] + red[1] + red[2] + red[3] + b_c[e];
  } else {
    if (threadIdx.x < 8) out_tail[threadIdx.x] = ptr[threadIdx.x];
    for (int i = threadIdx.x; i < N; i += 256) out_tail[8 + i] = 0.f;
  }
}

// ---------------- kernel 2: wv[m,y] ----------------
// wv[m,y] = mono[m,y] * sum_e cm[e]*(-(I-fe)^2 + relu(I+fe))
// I = (m==0) ? query[e] : feat[(m-1), y, e]
__global__ __launch_bounds__(256) void k_wv(
    const float* __restrict__ feat, const float* __restrict__ fe,
    const float* __restrict__ mono, const float* __restrict__ cm,
    const float* __restrict__ query, float* __restrict__ wv) {
  int gid = blockIdx.x * 256 + threadIdx.x;      // m*N + y
  int m = gid >> 10;
  int y = gid & (N - 1);
  const float4* src = (m == 0)
      ? (const float4*)query
      : (const float4*)(feat + ((size_t)(m - 1) * N + y) * E);
  const float4* fev = (const float4*)(fe + (size_t)y * E);
  const float4* cmv = (const float4*)cm;
  float s = 0.f;
  #pragma unroll
  for (int j = 0; j < E / 4; ++j) {
    float4 a = src[j];
    float4 f = fev[j];
    float4 c = cmv[j];
    float dx = a.x - f.x, dy = a.y - f.y, dz = a.z - f.z, dw = a.w - f.w;
    s += c.x * (fmaxf(a.x + f.x, 0.f) - dx * dx);
    s += c.y * (fmaxf(a.y + f.y, 0.f) - dy * dy);
    s += c.z * (fmaxf(a.z + f.z, 0.f) - dz * dz);
    s += c.w * (fmaxf(a.w + f.w, 0.f) - dw * dw);
  }
  wv[gid] = mono[gid] * s;
}

// ---------------- kernel 3: P[j,i] = sum_l att_stack[j,i,l]*ptr[l] -------
__global__ __launch_bounds__(256) void k_P(
    const float* __restrict__ att_stack, const float* __restrict__ ptr,
    float* __restrict__ P) {
  int gid = blockIdx.x * 256 + threadIdx.x;      // j*N + i
  const float4* a = (const float4*)(att_stack + (size_t)gid * L);
  float4 a0 = a[0], a1 = a[1];
  float s = a0.x * ptr[0] + a0.y * ptr[1] + a0.z * ptr[2] + a0.w * ptr[3]
          + a1.x * ptr[4] + a1.y * ptr[5] + a1.z * ptr[6] + a1.w * ptr[7];
  P[gid] = s;
}

// ---------------- kernel 4: att_out = P^T @ wv^T (fp32 VALU) -------------
// C[x,m] = sum_k P[k,x] * wv[m,k].  64x64 tile, 4x4 per thread, BK=16.
// Grid 256 blocks = full chip at 1 block/CU.
#define BK 16
__global__ __launch_bounds__(256) void k_mm(
    const float* __restrict__ P, const float* __restrict__ wv,
    float* __restrict__ C) {
  __shared__ float As[BK][64];
  __shared__ float Bs[BK][68];   // stride 68: store-bank shift of 16 -> 2-way max
  int tid = threadIdx.x;
  int x0 = (blockIdx.x & 15) * 64;
  int m0 = (blockIdx.x >> 4) * 64;
  int tx = tid & 15;             // m direction
  int ty = tid >> 4;             // x direction
  int la_k = tid >> 4;           // 0..15
  int la_c = (tid & 15) * 4;     // 0..60
  int lb_n = tid >> 2;           // 0..63
  int lb_k = (tid & 3) * 4;      // 0,4,8,12
  float acc[4][4] = {};
  for (int k0 = 0; k0 < N; k0 += BK) {
    float4 av = *(const float4*)&P[(size_t)(k0 + la_k) * N + x0 + la_c];
    float4 bv = *(const float4*)&wv[(size_t)(m0 + lb_n) * N + k0 + lb_k];
    __syncthreads();
    *(float4*)&As[la_k][la_c] = av;
    Bs[lb_k + 0][lb_n] = bv.x;
    Bs[lb_k + 1][lb_n] = bv.y;
    Bs[lb_k + 2][lb_n] = bv.z;
    Bs[lb_k + 3][lb_n] = bv.w;
    __syncthreads();
    #pragma unroll
    for (int k = 0; k < BK; ++k) {
      float4 a = *(const float4*)&As[k][ty * 4];
      float4 b = *(const float4*)&Bs[k][tx * 4];
      float ar[4] = {a.x, a.y, a.z, a.w};
      float br[4] = {b.x, b.y, b.z, b.w};
      #pragma unroll
      for (int r = 0; r < 4; ++r)
        #pragma unroll
        for (int c = 0; c < 4; ++c)
          acc[r][c] = fmaf(ar[r], br[c], acc[r][c]);
    }
  }
  #pragma unroll
  for (int r = 0; r < 4; ++r) {
    float4 o = {acc[r][0], acc[r][1], acc[r][2], acc[r][3]};
    *(float4*)&C[(size_t)(x0 + ty * 4 + r) * N + m0 + tx * 4] = o;
  }
}

// ---------------- kernel 5: norm[m] = max_x C[x,m]; <=1 -> 1 -------------
__global__ __launch_bounds__(1024) void k_norm(
    const float* __restrict__ C, float* __restrict__ norm) {
  int tx = threadIdx.x & 63;     // m within group of 64
  int ty = threadIdx.x >> 6;     // 0..15, x stride
  int m = blockIdx.x * 64 + tx;
  float mx = -INFINITY;
  for (int x = ty; x < N; x += 16)
    mx = fmaxf(mx, C[(size_t)x * N + m]);
  __shared__ float red[16][64];
  red[ty][tx] = mx;
  __syncthreads();
  if (ty == 0) {
    #pragma unroll
    for (int j = 1; j < 16; ++j) mx = fmaxf(mx, red[j][tx]);
    norm[m] = (mx <= 1.f) ? 1.f : mx;
  }
}

// ---------------- kernel 6: blend + write output -------------------------
__global__ __launch_bounds__(256) void k_blend(
    const float* __restrict__ C, const float* __restrict__ norm,
    const float* __restrict__ att_stack, const float* __restrict__ ptr,
    float* __restrict__ out) {
  int gid = blockIdx.x * 256 + threadIdx.x;   // x*N + m
  int m = gid & (N - 1);
  float a = C[gid] / norm[m];
  const float4* s = (const float4*)(att_stack + (size_t)gid * L);
  float4 s0 = s[0], s1 = s[1];
  float p0 = ptr[0], p1 = ptr[1], p2 = ptr[2], p3 = ptr[3];
  float p4 = ptr[4], p5 = ptr[5], p6 = ptr[6], p7 = ptr[7];
  float4 o0, o1;
  o0.x = a * p0 + s0.x * (1.f - p0);
  o0.y = a * p1 + s0.y * (1.f - p1);
  o0.z = a * p2 + s0.z * (1.f - p2);
  o0.w = a * p3 + s0.w * (1.f - p3);
  o1.x = a * p4 + s1.x * (1.f - p4);
  o1.y = a * p5 + s1.y * (1.f - p5);
  o1.z = a * p6 + s1.z * (1.f - p6);
  o1.w = a * p7 + s1.w * (1.f - p7);
  float4* o = (float4*)(out + (size_t)gid * L);
  o[0] = o0;
  o[1] = o1;
}

extern "C" void kernel_launch(void* const* d_in, const int* in_sizes, int n_in,
                              void* d_out, int out_size, void* d_ws, size_t ws_size,
                              hipStream_t stream) {
  const float* feat      = (const float*)d_in[1];
  const float* feat_edge = (const float*)d_in[2];
  const float* c_i       = (const float*)d_in[3];
  const float* att_stack = (const float*)d_in[5];
  const float* stack_ptr = (const float*)d_in[6];
  const float* mono_mask = (const float*)d_in[8];
  const float* cross_mask= (const float*)d_in[9];
  const float* w_c       = (const float*)d_in[10];
  const float* b_c       = (const float*)d_in[11];

  float* out = (float*)d_out;
  float* ws  = (float*)d_ws;

  // ws layout (floats)
  float* query = ws;                                  // 32 (padded to 64)
  float* wv    = ws + 64;                             // N*N
  float* P     = ws + 64 + (size_t)N * N;             // N*N
  float* C     = ws + 64 + (size_t)2 * N * N;         // N*N
  float* norm  = ws + 64 + (size_t)3 * N * N;         // N

  float* out_tail = out + (size_t)N * N * L;          // stack_ptr + mem zeros

  k_query_tail<<<33, 256, 0, stream>>>(c_i, w_c, b_c, stack_ptr, query, out_tail);
  k_wv<<<(N * N) / 256, 256, 0, stream>>>(feat, feat_edge, mono_mask, cross_mask,
                                          query, wv);
  k_P<<<(N * N) / 256, 256, 0, stream>>>(att_stack, stack_ptr, P);
  k_mm<<<256, 256, 0, stream>>>(P, wv, C);
  k_norm<<<16, 1024, 0, stream>>>(C, norm);
  k_blend<<<(N * N) / 256, 256, 0, stream>>>(C, norm, att_stack, stack_ptr, out);
}

// Round 3
// 337.811 us; speedup vs baseline: 1.0389x; 1.0389x over previous
//
#include <hip/hip_runtime.h>
#include <math.h>

#define N 1024
#define E 32
#define L 8

// ---------------- kernel 1: query + output tail ----------------
// blocks 0..31: query[e] = b_c[e] + dot(c_i, w_c[e,:])
// block 32: d_out tail = stack_ptr (8) + zeros (1024)
__global__ __launch_bounds__(256) void k_query_tail(
    const float* __restrict__ c_i, const float* __restrict__ w_c,
    const float* __restrict__ b_c, const float* __restrict__ ptr,
    float* __restrict__ query, float* __restrict__ out_tail) {
  int b = blockIdx.x;
  if (b < 32) {
    int e = b;
    float s = 0.f;
    for (int h = threadIdx.x; h < N; h += 256)
      s += c_i[h] * w_c[e * N + h];
    #pragma unroll
    for (int off = 32; off > 0; off >>= 1)
      s += __shfl_down(s, off, 64);
    __shared__ float red[4];
    if ((threadIdx.x & 63) == 0) red[threadIdx.x >> 6] = s;
    __syncthreads();
    if (threadIdx.x == 0)
      query[e] = red[0] + red[1] + red[2] + red[3] + b_c[e];
  } else {
    if (threadIdx.x < 8) out_tail[threadIdx.x] = ptr[threadIdx.x];
    for (int i = threadIdx.x; i < N; i += 256) out_tail[8 + i] = 0.f;
  }
}

// ---------------- kernel 2: wv[m,y] ----------------
// wv[m,y] = mono[m,y] * sum_e cm[e]*(-(I-fe)^2 + relu(I+fe))
// I = (m==0) ? query[e] : feat[(m-1), y, e]
__global__ __launch_bounds__(256) void k_wv(
    const float* __restrict__ feat, const float* __restrict__ fe,
    const float* __restrict__ mono, const float* __restrict__ cm,
    const float* __restrict__ query, float* __restrict__ wv) {
  int gid = blockIdx.x * 256 + threadIdx.x;      // m*N + y
  int m = gid >> 10;
  int y = gid & (N - 1);
  const float4* src = (m == 0)
      ? (const float4*)query
      : (const float4*)(feat + ((size_t)(m - 1) * N + y) * E);
  const float4* fev = (const float4*)(fe + (size_t)y * E);
  const float4* cmv = (const float4*)cm;
  float s = 0.f;
  #pragma unroll
  for (int j = 0; j < E / 4; ++j) {
    float4 a = src[j];
    float4 f = fev[j];
    float4 c = cmv[j];
    float dx = a.x - f.x, dy = a.y - f.y, dz = a.z - f.z, dw = a.w - f.w;
    s += c.x * (fmaxf(a.x + f.x, 0.f) - dx * dx);
    s += c.y * (fmaxf(a.y + f.y, 0.f) - dy * dy);
    s += c.z * (fmaxf(a.z + f.z, 0.f) - dz * dz);
    s += c.w * (fmaxf(a.w + f.w, 0.f) - dw * dw);
  }
  wv[gid] = mono[gid] * s;
}

// ---------------- kernel 3: P[j,i] = sum_l att_stack[j,i,l]*ptr[l] -------
__global__ __launch_bounds__(256) void k_P(
    const float* __restrict__ att_stack, const float* __restrict__ ptr,
    float* __restrict__ P) {
  int gid = blockIdx.x * 256 + threadIdx.x;      // j*N + i
  const float4* a = (const float4*)(att_stack + (size_t)gid * L);
  float4 a0 = a[0], a1 = a[1];
  float s = a0.x * ptr[0] + a0.y * ptr[1] + a0.z * ptr[2] + a0.w * ptr[3]
          + a1.x * ptr[4] + a1.y * ptr[5] + a1.z * ptr[6] + a1.w * ptr[7];
  P[gid] = s;
}

// ---------------- kernel 4: att_out partials (split-K fp32 VALU) ---------
// Cp[kc][x][m] = sum_{k in chunk kc} P[k,x] * wv[m,k].
// 64x64 tile, 4x4 per thread, BK=16, KCHUNK=256.
// Grid (16,16,4) = 1024 blocks -> 4 blocks/CU -> 4 waves/SIMD.
#define BK 16
#define KCHUNK 256
__global__ __launch_bounds__(256) void k_mm(
    const float* __restrict__ P, const float* __restrict__ wv,
    float* __restrict__ Cp) {
  __shared__ float As[BK][64];
  __shared__ float Bs[BK][68];   // stride 68: break power-of-2 bank stride
  int tid = threadIdx.x;
  int x0 = blockIdx.x * 64;
  int m0 = blockIdx.y * 64;
  int kb = blockIdx.z * KCHUNK;
  int tx = tid & 15;             // m direction
  int ty = tid >> 4;             // x direction
  int la_k = tid >> 4;           // 0..15
  int la_c = (tid & 15) * 4;     // 0..60
  int lb_n = tid >> 2;           // 0..63
  int lb_k = (tid & 3) * 4;      // 0,4,8,12
  float acc[4][4] = {};
  for (int k0 = kb; k0 < kb + KCHUNK; k0 += BK) {
    float4 av = *(const float4*)&P[(size_t)(k0 + la_k) * N + x0 + la_c];
    float4 bv = *(const float4*)&wv[(size_t)(m0 + lb_n) * N + k0 + lb_k];
    __syncthreads();
    *(float4*)&As[la_k][la_c] = av;
    Bs[lb_k + 0][lb_n] = bv.x;
    Bs[lb_k + 1][lb_n] = bv.y;
    Bs[lb_k + 2][lb_n] = bv.z;
    Bs[lb_k + 3][lb_n] = bv.w;
    __syncthreads();
    #pragma unroll
    for (int k = 0; k < BK; ++k) {
      float4 a = *(const float4*)&As[k][ty * 4];
      float4 b = *(const float4*)&Bs[k][tx * 4];
      float ar[4] = {a.x, a.y, a.z, a.w};
      float br[4] = {b.x, b.y, b.z, b.w};
      #pragma unroll
      for (int r = 0; r < 4; ++r)
        #pragma unroll
        for (int c = 0; c < 4; ++c)
          acc[r][c] = fmaf(ar[r], br[c], acc[r][c]);
    }
  }
  float* Cc = Cp + (size_t)blockIdx.z * N * N;
  #pragma unroll
  for (int r = 0; r < 4; ++r) {
    float4 o = {acc[r][0], acc[r][1], acc[r][2], acc[r][3]};
    *(float4*)&Cc[(size_t)(x0 + ty * 4 + r) * N + m0 + tx * 4] = o;
  }
}

// ---------------- kernel 5: reduce split-K + partial column max ----------
// Grid 128 blocks x 1024 threads. Block xg owns x rows [xg*8, xg*8+8).
// Thread m = threadIdx.x owns column m within those rows. No LDS needed.
__global__ __launch_bounds__(1024) void k_rednorm(
    const float* __restrict__ Cp, float* __restrict__ C,
    float* __restrict__ normp) {
  int m = threadIdx.x;
  int xg = blockIdx.x;
  float mx = -INFINITY;
  #pragma unroll
  for (int j = 0; j < 8; ++j) {
    size_t idx = (size_t)(xg * 8 + j) * N + m;
    float s = Cp[idx] + Cp[idx + (size_t)N * N] + Cp[idx + (size_t)2 * N * N]
            + Cp[idx + (size_t)3 * N * N];
    C[idx] = s;
    mx = fmaxf(mx, s);
  }
  normp[(size_t)xg * N + m] = mx;
}

// ---------------- kernel 6: finish norm: max over 128 partials, <=1 -> 1 --
__global__ __launch_bounds__(256) void k_norm2(
    const float* __restrict__ normp, float* __restrict__ norm) {
  int m = blockIdx.x * 256 + threadIdx.x;
  float mx = -INFINITY;
  #pragma unroll 8
  for (int xg = 0; xg < 128; ++xg)
    mx = fmaxf(mx, normp[(size_t)xg * N + m]);
  norm[m] = (mx <= 1.f) ? 1.f : mx;
}

// ---------------- kernel 7: blend + write output -------------------------
__global__ __launch_bounds__(256) void k_blend(
    const float* __restrict__ C, const float* __restrict__ norm,
    const float* __restrict__ att_stack, const float* __restrict__ ptr,
    float* __restrict__ out) {
  int gid = blockIdx.x * 256 + threadIdx.x;   // x*N + m
  int m = gid & (N - 1);
  float a = C[gid] / norm[m];
  const float4* s = (const float4*)(att_stack + (size_t)gid * L);
  float4 s0 = s[0], s1 = s[1];
  float p0 = ptr[0], p1 = ptr[1], p2 = ptr[2], p3 = ptr[3];
  float p4 = ptr[4], p5 = ptr[5], p6 = ptr[6], p7 = ptr[7];
  float4 o0, o1;
  o0.x = a * p0 + s0.x * (1.f - p0);
  o0.y = a * p1 + s0.y * (1.f - p1);
  o0.z = a * p2 + s0.z * (1.f - p2);
  o0.w = a * p3 + s0.w * (1.f - p3);
  o1.x = a * p4 + s1.x * (1.f - p4);
  o1.y = a * p5 + s1.y * (1.f - p5);
  o1.z = a * p6 + s1.z * (1.f - p6);
  o1.w = a * p7 + s1.w * (1.f - p7);
  float4* o = (float4*)(out + (size_t)gid * L);
  o[0] = o0;
  o[1] = o1;
}

extern "C" void kernel_launch(void* const* d_in, const int* in_sizes, int n_in,
                              void* d_out, int out_size, void* d_ws, size_t ws_size,
                              hipStream_t stream) {
  const float* feat      = (const float*)d_in[1];
  const float* feat_edge = (const float*)d_in[2];
  const float* c_i       = (const float*)d_in[3];
  const float* att_stack = (const float*)d_in[5];
  const float* stack_ptr = (const float*)d_in[6];
  const float* mono_mask = (const float*)d_in[8];
  const float* cross_mask= (const float*)d_in[9];
  const float* w_c       = (const float*)d_in[10];
  const float* b_c       = (const float*)d_in[11];

  float* out = (float*)d_out;
  float* ws  = (float*)d_ws;

  // ws layout (floats); total ~29.9 MB, well under ws_size (~0.5 GB per R1 fills)
  float* query = ws;                                   // 64
  float* wv    = ws + 64;                              // N*N
  float* P     = wv + (size_t)N * N;                   // N*N
  float* C     = P + (size_t)N * N;                    // N*N
  float* norm  = C + (size_t)N * N;                    // 1024
  float* normp = norm + 1024;                          // 128*N
  float* Cp    = normp + (size_t)128 * N;              // 4*N*N

  float* out_tail = out + (size_t)N * N * L;           // stack_ptr + mem zeros

  k_query_tail<<<33, 256, 0, stream>>>(c_i, w_c, b_c, stack_ptr, query, out_tail);
  k_wv<<<(N * N) / 256, 256, 0, stream>>>(feat, feat_edge, mono_mask, cross_mask,
                                          query, wv);
  k_P<<<(N * N) / 256, 256, 0, stream>>>(att_stack, stack_ptr, P);
  dim3 mmgrid(16, 16, 4);
  k_mm<<<mmgrid, 256, 0, stream>>>(P, wv, Cp);
  k_rednorm<<<128, 1024, 0, stream>>>(Cp, C, normp);
  k_norm2<<<4, 256, 0, stream>>>(normp, norm);
  k_blend<<<(N * N) / 256, 256, 0, stream>>>(C, norm, att_stack, stack_ptr, out);
}

// Round 4
// 332.943 us; speedup vs baseline: 1.0540x; 1.0146x over previous
//
#include <hip/hip_runtime.h>
#include <math.h>

#define N 1024
#define E 32
#define L 8
#define NN ((size_t)N * N)

using short8 = __attribute__((ext_vector_type(8))) short;
using f32x4v = __attribute__((ext_vector_type(4))) float;

// split fp32 into bf16 hi + bf16 lo (truncation; residual ~2^-16 relative)
__device__ inline ushort2 split_bf16(float v) {
  unsigned ui = __float_as_uint(v);
  ushort h = (ushort)(ui >> 16);
  float hv = __uint_as_float((unsigned)h << 16);
  float r = v - hv;
  ushort l = (ushort)(__float_as_uint(r) >> 16);
  return make_ushort2(h, l);
}

// async global->LDS, 16B per lane; lds dest = wave-uniform base + lane*16
__device__ inline void gload16(const void* g, void* l) {
  __builtin_amdgcn_global_load_lds(
      (const __attribute__((address_space(1))) unsigned int*)g,
      (__attribute__((address_space(3))) unsigned int*)l, 16, 0, 0);
}

// ---------------- kernel 1: prep = query + wv(hi/lo) + P-transpose(hi/lo) + tail
// blocks [0,4096):      wv[m,y] -> wv_h/wv_l (blocks 0..3 compute query in LDS)
// blocks [4096,4352):   P[j,i] = att_stack.ptr, transposed -> Pt_h/Pt_l [i][j]
// block 4352:           out tail = stack_ptr + zeros
__global__ __launch_bounds__(256) void k_prep(
    const float* __restrict__ feat, const float* __restrict__ fe,
    const float* __restrict__ mono, const float* __restrict__ cm,
    const float* __restrict__ c_i, const float* __restrict__ w_c,
    const float* __restrict__ b_c, const float* __restrict__ att_stack,
    const float* __restrict__ ptr,
    ushort* __restrict__ wv_h, ushort* __restrict__ wv_l,
    ushort* __restrict__ Pt_h, ushort* __restrict__ Pt_l,
    float* __restrict__ out_tail) {
  __shared__ __align__(16) float qsm[32];
  __shared__ ushort Ts[2][64][66];   // pad 66: conflict-free column writes
  int b = blockIdx.x;
  int tid = threadIdx.x;
  if (b < 4096) {
    int gid = b * 256 + tid;          // m*N + y
    int m = gid >> 10;
    int y = gid & (N - 1);
    if (b < 4) {                      // m==0 blocks: compute query cooperatively
      int e = tid >> 3, r = tid & 7;
      float s = 0.f;
      for (int h = r; h < N; h += 8) s += c_i[h] * w_c[e * N + h];
      #pragma unroll
      for (int off = 4; off > 0; off >>= 1) s += __shfl_down(s, off, 8);
      if (r == 0) qsm[e] = s + b_c[e];
      __syncthreads();
    }
    const float* src = (m == 0)
        ? (const float*)qsm
        : (feat + ((size_t)(m - 1) * N + y) * E);
    const float4* sv  = (const float4*)src;
    const float4* fev = (const float4*)(fe + (size_t)y * E);
    const float4* cmv = (const float4*)cm;
    float s = 0.f;
    #pragma unroll
    for (int j = 0; j < E / 4; ++j) {
      float4 a = sv[j];
      float4 f = fev[j];
      float4 c = cmv[j];
      float dx = a.x - f.x, dy = a.y - f.y, dz = a.z - f.z, dw = a.w - f.w;
      s += c.x * (fmaxf(a.x + f.x, 0.f) - dx * dx);
      s += c.y * (fmaxf(a.y + f.y, 0.f) - dy * dy);
      s += c.z * (fmaxf(a.z + f.z, 0.f) - dz * dz);
      s += c.w * (fmaxf(a.w + f.w, 0.f) - dw * dw);
    }
    float v = mono[gid] * s;
    ushort2 hl = split_bf16(v);
    wv_h[gid] = hl.x;
    wv_l[gid] = hl.y;
  } else if (b < 4096 + 256) {
    int pb = b - 4096;
    int j0 = (pb >> 4) * 64;          // k-dim of Pt
    int i0 = (pb & 15) * 64;          // x-dim of Pt
    float p0 = ptr[0], p1 = ptr[1], p2 = ptr[2], p3 = ptr[3];
    float p4 = ptr[4], p5 = ptr[5], p6 = ptr[6], p7 = ptr[7];
    int w = tid >> 6, lane = tid & 63;
    #pragma unroll 4
    for (int r = 0; r < 16; ++r) {
      int jl = r * 4 + w;
      int il = lane;
      const float4* a =
          (const float4*)(att_stack + ((size_t)(j0 + jl) * N + i0 + il) * L);
      float4 a0 = a[0], a1 = a[1];
      float s = a0.x * p0 + a0.y * p1 + a0.z * p2 + a0.w * p3
              + a1.x * p4 + a1.y * p5 + a1.z * p6 + a1.w * p7;
      ushort2 hl = split_bf16(s);
      Ts[0][il][jl] = hl.x;
      Ts[1][il][jl] = hl.y;
    }
    __syncthreads();
    int il = tid >> 2, c = tid & 3;
    size_t o = (size_t)(i0 + il) * N + j0 + c * 16;
    {
      const uint* sp = (const uint*)&Ts[0][il][c * 16];
      uint4 d0 = {sp[0], sp[1], sp[2], sp[3]};
      uint4 d1 = {sp[4], sp[5], sp[6], sp[7]};
      *(uint4*)&Pt_h[o] = d0;
      *(uint4*)&Pt_h[o + 8] = d1;
    }
    {
      const uint* sp = (const uint*)&Ts[1][il][c * 16];
      uint4 d0 = {sp[0], sp[1], sp[2], sp[3]};
      uint4 d1 = {sp[4], sp[5], sp[6], sp[7]};
      *(uint4*)&Pt_l[o] = d0;
      *(uint4*)&Pt_l[o + 8] = d1;
    }
  } else {
    if (tid < 8) out_tail[tid] = ptr[tid];
    for (int i = tid; i < N; i += 256) out_tail[8 + i] = 0.f;
  }
}

// ---------------- kernel 2: split-K MFMA matmul ---------------------------
// Cp[kc][x][m] = sum_{k in chunk} Pt[x][k] * wv[m][k], bf16 hi/lo (3 products)
// 64x64 tile, BK=32, KCHUNK=256; grid (16,16,4) -> 4 blocks/CU.
__global__ __launch_bounds__(256) void k_mm(
    const ushort* __restrict__ Pt_h, const ushort* __restrict__ Pt_l,
    const ushort* __restrict__ wv_h, const ushort* __restrict__ wv_l,
    float* __restrict__ Cp) {
  __shared__ ushort As[2][64][32];
  __shared__ ushort Bs[2][64][32];
  int tid = threadIdx.x;
  int lane = tid & 63, w = tid >> 6;
  int x0 = blockIdx.x * 64, m0 = blockIdx.y * 64;
  int kb = blockIdx.z * 256;
  // staging: wave w stages rows [w*16, w*16+16); lane covers (row, 16B chunk)
  int srow = w * 16 + (lane >> 2);
  int scol = (lane & 3) * 8;   // halves
  const ushort* gAh = Pt_h + (size_t)(x0 + srow) * N + kb + scol;
  const ushort* gAl = Pt_l + (size_t)(x0 + srow) * N + kb + scol;
  const ushort* gBh = wv_h + (size_t)(m0 + srow) * N + kb + scol;
  const ushort* gBl = wv_l + (size_t)(m0 + srow) * N + kb + scol;
  ushort* lAh = &As[0][w * 16][0];
  ushort* lAl = &As[1][w * 16][0];
  ushort* lBh = &Bs[0][w * 16][0];
  ushort* lBl = &Bs[1][w * 16][0];
  // fragment indices (verified gemm_bt layout: out=lane&15, k=(lane>>4)*8+j)
  int fr = w * 16 + (lane & 15);
  int fk = (lane >> 4) * 8;
  int fn = lane & 15;
  f32x4v acc[4];
  #pragma unroll
  for (int t = 0; t < 4; ++t) acc[t] = (f32x4v){0.f, 0.f, 0.f, 0.f};
  for (int kt = 0; kt < 8; ++kt) {
    __syncthreads();
    gload16(gAh + kt * 32, lAh);
    gload16(gAl + kt * 32, lAl);
    gload16(gBh + kt * 32, lBh);
    gload16(gBl + kt * 32, lBl);
    __syncthreads();   // compiler emits vmcnt(0) drain here
    short8 Ah = *(const short8*)&As[0][fr][fk];
    short8 Al = *(const short8*)&As[1][fr][fk];
    #pragma unroll
    for (int t = 0; t < 4; ++t) {
      short8 Bh = *(const short8*)&Bs[0][t * 16 + fn][fk];
      short8 Bl = *(const short8*)&Bs[1][t * 16 + fn][fk];
      acc[t] = __builtin_amdgcn_mfma_f32_16x16x32_bf16(Ah, Bh, acc[t], 0, 0, 0);
      acc[t] = __builtin_amdgcn_mfma_f32_16x16x32_bf16(Ah, Bl, acc[t], 0, 0, 0);
      acc[t] = __builtin_amdgcn_mfma_f32_16x16x32_bf16(Al, Bh, acc[t], 0, 0, 0);
    }
  }
  // C/D layout: col = lane&15, row = (lane>>4)*4 + reg  [m89-verified]
  float* Cc = Cp + (size_t)blockIdx.z * NN;
  int orow = x0 + w * 16 + (lane >> 4) * 4;
  int ocol = m0 + fn;
  #pragma unroll
  for (int t = 0; t < 4; ++t)
    #pragma unroll
    for (int r = 0; r < 4; ++r)
      Cc[(size_t)(orow + r) * N + ocol + t * 16] = acc[t][r];
}

// ---------------- kernel 3: reduce split-K + partial column max ----------
__global__ __launch_bounds__(1024) void k_rednorm(
    const float* __restrict__ Cp, float* __restrict__ C,
    float* __restrict__ normp) {
  int m = threadIdx.x;
  int xg = blockIdx.x;    // 0..255, 4 rows each
  float mx = -INFINITY;
  #pragma unroll
  for (int j = 0; j < 4; ++j) {
    size_t idx = (size_t)(xg * 4 + j) * N + m;
    float s = Cp[idx] + Cp[idx + NN] + Cp[idx + 2 * NN] + Cp[idx + 3 * NN];
    C[idx] = s;
    mx = fmaxf(mx, s);
  }
  normp[(size_t)xg * N + m] = mx;
}

// ---------------- kernel 4: finish norm ----------------------------------
__global__ __launch_bounds__(256) void k_norm2(
    const float* __restrict__ normp, float* __restrict__ norm) {
  int m = blockIdx.x * 256 + threadIdx.x;
  float mx = -INFINITY;
  #pragma unroll 8
  for (int xg = 0; xg < 256; ++xg)
    mx = fmaxf(mx, normp[(size_t)xg * N + m]);
  norm[m] = (mx <= 1.f) ? 1.f : mx;
}

// ---------------- kernel 5: blend + write output -------------------------
__global__ __launch_bounds__(256) void k_blend(
    const float* __restrict__ C, const float* __restrict__ norm,
    const float* __restrict__ att_stack, const float* __restrict__ ptr,
    float* __restrict__ out) {
  int gid = blockIdx.x * 256 + threadIdx.x;   // x*N + m
  int m = gid & (N - 1);
  float a = C[gid] / norm[m];
  const float4* s = (const float4*)(att_stack + (size_t)gid * L);
  float4 s0 = s[0], s1 = s[1];
  float p0 = ptr[0], p1 = ptr[1], p2 = ptr[2], p3 = ptr[3];
  float p4 = ptr[4], p5 = ptr[5], p6 = ptr[6], p7 = ptr[7];
  float4 o0, o1;
  o0.x = a * p0 + s0.x * (1.f - p0);
  o0.y = a * p1 + s0.y * (1.f - p1);
  o0.z = a * p2 + s0.z * (1.f - p2);
  o0.w = a * p3 + s0.w * (1.f - p3);
  o1.x = a * p4 + s1.x * (1.f - p4);
  o1.y = a * p5 + s1.y * (1.f - p5);
  o1.z = a * p6 + s1.z * (1.f - p6);
  o1.w = a * p7 + s1.w * (1.f - p7);
  float4* o = (float4*)(out + (size_t)gid * L);
  o[0] = o0;
  o[1] = o1;
}

extern "C" void kernel_launch(void* const* d_in, const int* in_sizes, int n_in,
                              void* d_out, int out_size, void* d_ws, size_t ws_size,
                              hipStream_t stream) {
  const float* feat      = (const float*)d_in[1];
  const float* feat_edge = (const float*)d_in[2];
  const float* c_i       = (const float*)d_in[3];
  const float* att_stack = (const float*)d_in[5];
  const float* stack_ptr = (const float*)d_in[6];
  const float* mono_mask = (const float*)d_in[8];
  const float* cross_mask= (const float*)d_in[9];
  const float* w_c       = (const float*)d_in[10];
  const float* b_c       = (const float*)d_in[11];

  float* out = (float*)d_out;

  // ws layout: 4 ushort planes (8 MB) then fp32 arrays (~22 MB)
  ushort* wv_h = (ushort*)d_ws;
  ushort* wv_l = wv_h + NN;
  ushort* Pt_h = wv_l + NN;
  ushort* Pt_l = Pt_h + NN;
  float*  Cp   = (float*)(Pt_l + NN);
  float*  C    = Cp + 4 * NN;
  float*  normp= C + NN;               // 256*N
  float*  norm = normp + (size_t)256 * N;

  float* out_tail = out + NN * L;      // stack_ptr + mem zeros

  k_prep<<<4353, 256, 0, stream>>>(feat, feat_edge, mono_mask, cross_mask,
                                   c_i, w_c, b_c, att_stack, stack_ptr,
                                   wv_h, wv_l, Pt_h, Pt_l, out_tail);
  dim3 mmgrid(16, 16, 4);
  k_mm<<<mmgrid, 256, 0, stream>>>(Pt_h, Pt_l, wv_h, wv_l, Cp);
  k_rednorm<<<256, 1024, 0, stream>>>(Cp, C, normp);
  k_norm2<<<4, 256, 0, stream>>>(normp, norm);
  k_blend<<<4096, 256, 0, stream>>>(C, norm, att_stack, stack_ptr, out);
}

// Round 5
// 321.561 us; speedup vs baseline: 1.0913x; 1.0354x over previous
//
#include <hip/hip_runtime.h>
#include <math.h>

#define N 1024
#define E 32
#define L 8
#define NN ((size_t)N * N)

using short8 = __attribute__((ext_vector_type(8))) short;
using f32x4v = __attribute__((ext_vector_type(4))) float;

// split fp32 into bf16 hi + bf16 lo (truncation; residual ~2^-16 relative)
__device__ inline ushort2 split_bf16(float v) {
  unsigned ui = __float_as_uint(v);
  ushort h = (ushort)(ui >> 16);
  float hv = __uint_as_float((unsigned)h << 16);
  float r = v - hv;
  ushort l = (ushort)(__float_as_uint(r) >> 16);
  return make_ushort2(h, l);
}

// async global->LDS, 16B per lane; lds dest = wave-uniform base + lane*16
__device__ inline void gload16(const void* g, void* l) {
  __builtin_amdgcn_global_load_lds(
      (const __attribute__((address_space(1))) unsigned int*)g,
      (__attribute__((address_space(3))) unsigned int*)l, 16, 0, 0);
}

// ---------------- kernel 1: wv (coalesced, 8 lanes per row) --------------
// wv[m,y] = mono[m,y] * sum_e cm[e]*(-(I-fe)^2 + relu(I+fe))
// Block = 256 threads = 32 rows; lane seg in [0,8) owns float4 #seg of row.
// Blocks 0..31 (m==0) compute query in LDS first (block-uniform branch).
__global__ __launch_bounds__(256) void k_wv(
    const float* __restrict__ feat, const float* __restrict__ fe,
    const float* __restrict__ mono, const float* __restrict__ cm,
    const float* __restrict__ c_i, const float* __restrict__ w_c,
    const float* __restrict__ b_c,
    ushort* __restrict__ wv_h, ushort* __restrict__ wv_l) {
  __shared__ __align__(16) float qsm[32];
  int tid = threadIdx.x;
  int b = blockIdx.x;
  int seg = tid & 7;
  int rl = tid >> 3;             // 0..31 local row
  int gid = b * 32 + rl;         // m*N + y
  int m = gid >> 10;
  int y = gid & (N - 1);
  if (b < 32) {                  // m==0: compute query cooperatively
    float s = 0.f;
    for (int h = seg; h < N; h += 8) s += c_i[h] * w_c[rl * N + h];
    s += __shfl_down(s, 4, 8);
    s += __shfl_down(s, 2, 8);
    s += __shfl_down(s, 1, 8);
    if (seg == 0) qsm[rl] = s + b_c[rl];
    __syncthreads();
  }
  float4 a;
  if (m == 0) {
    a = *((const float4*)qsm + seg);                       // LDS broadcast
  } else {
    a = *(const float4*)(feat + ((size_t)(m - 1) * N + y) * E + seg * 4);
  }
  float4 f = *(const float4*)(fe + (size_t)y * E + seg * 4);
  float4 c = *(const float4*)(cm + seg * 4);
  float dx = a.x - f.x, dy = a.y - f.y, dz = a.z - f.z, dw = a.w - f.w;
  float s = c.x * (fmaxf(a.x + f.x, 0.f) - dx * dx)
          + c.y * (fmaxf(a.y + f.y, 0.f) - dy * dy)
          + c.z * (fmaxf(a.z + f.z, 0.f) - dz * dz)
          + c.w * (fmaxf(a.w + f.w, 0.f) - dw * dw);
  s += __shfl_down(s, 4, 8);
  s += __shfl_down(s, 2, 8);
  s += __shfl_down(s, 1, 8);
  if (seg == 0) {
    float v = mono[gid] * s;
    ushort2 hl = split_bf16(v);
    wv_h[gid] = hl.x;
    wv_l[gid] = hl.y;
  }
}

// ---------------- kernel 2: P-transpose (hi/lo) + output tail ------------
// blocks [0,256): P[j,i] = att_stack[j,i,:].ptr, stored transposed Pt[i][j]
// block 256: out tail = stack_ptr + zeros
__global__ __launch_bounds__(256) void k_P(
    const float* __restrict__ att_stack, const float* __restrict__ ptr,
    ushort* __restrict__ Pt_h, ushort* __restrict__ Pt_l,
    float* __restrict__ out_tail) {
  __shared__ ushort Ts[2][64][66];   // pad 66: conflict-free column writes
  int tid = threadIdx.x;
  int b = blockIdx.x;
  if (b < 256) {
    int j0 = (b >> 4) * 64;          // k-dim of Pt
    int i0 = (b & 15) * 64;          // x-dim of Pt
    float p0 = ptr[0], p1 = ptr[1], p2 = ptr[2], p3 = ptr[3];
    float p4 = ptr[4], p5 = ptr[5], p6 = ptr[6], p7 = ptr[7];
    int w = tid >> 6, lane = tid & 63;
    #pragma unroll 4
    for (int r = 0; r < 16; ++r) {
      int jl = r * 4 + w;
      int il = lane;
      const float4* a =
          (const float4*)(att_stack + ((size_t)(j0 + jl) * N + i0 + il) * L);
      float4 a0 = a[0], a1 = a[1];
      float s = a0.x * p0 + a0.y * p1 + a0.z * p2 + a0.w * p3
              + a1.x * p4 + a1.y * p5 + a1.z * p6 + a1.w * p7;
      ushort2 hl = split_bf16(s);
      Ts[0][il][jl] = hl.x;
      Ts[1][il][jl] = hl.y;
    }
    __syncthreads();
    int il = tid >> 2, c = tid & 3;
    size_t o = (size_t)(i0 + il) * N + j0 + c * 16;
    {
      const uint* sp = (const uint*)&Ts[0][il][c * 16];
      uint4 d0 = {sp[0], sp[1], sp[2], sp[3]};
      uint4 d1 = {sp[4], sp[5], sp[6], sp[7]};
      *(uint4*)&Pt_h[o] = d0;
      *(uint4*)&Pt_h[o + 8] = d1;
    }
    {
      const uint* sp = (const uint*)&Ts[1][il][c * 16];
      uint4 d0 = {sp[0], sp[1], sp[2], sp[3]};
      uint4 d1 = {sp[4], sp[5], sp[6], sp[7]};
      *(uint4*)&Pt_l[o] = d0;
      *(uint4*)&Pt_l[o + 8] = d1;
    }
  } else {
    if (tid < 8) out_tail[tid] = ptr[tid];
    for (int i = tid; i < N; i += 256) out_tail[8 + i] = 0.f;
  }
}

// ---------------- kernel 3: split-K MFMA matmul ---------------------------
// Cp[kc][x][m] = sum_{k in chunk} Pt[x][k] * wv[m][k], bf16 hi/lo (3 products)
// 64x64 tile, BK=32, KCHUNK=256; grid (16,16,4) -> 4 blocks/CU.
__global__ __launch_bounds__(256) void k_mm(
    const ushort* __restrict__ Pt_h, const ushort* __restrict__ Pt_l,
    const ushort* __restrict__ wv_h, const ushort* __restrict__ wv_l,
    float* __restrict__ Cp) {
  __shared__ ushort As[2][64][32];
  __shared__ ushort Bs[2][64][32];
  int tid = threadIdx.x;
  int lane = tid & 63, w = tid >> 6;
  int x0 = blockIdx.x * 64, m0 = blockIdx.y * 64;
  int kb = blockIdx.z * 256;
  int srow = w * 16 + (lane >> 2);
  int scol = (lane & 3) * 8;   // halves
  const ushort* gAh = Pt_h + (size_t)(x0 + srow) * N + kb + scol;
  const ushort* gAl = Pt_l + (size_t)(x0 + srow) * N + kb + scol;
  const ushort* gBh = wv_h + (size_t)(m0 + srow) * N + kb + scol;
  const ushort* gBl = wv_l + (size_t)(m0 + srow) * N + kb + scol;
  ushort* lAh = &As[0][w * 16][0];
  ushort* lAl = &As[1][w * 16][0];
  ushort* lBh = &Bs[0][w * 16][0];
  ushort* lBl = &Bs[1][w * 16][0];
  int fr = w * 16 + (lane & 15);
  int fk = (lane >> 4) * 8;
  int fn = lane & 15;
  f32x4v acc[4];
  #pragma unroll
  for (int t = 0; t < 4; ++t) acc[t] = (f32x4v){0.f, 0.f, 0.f, 0.f};
  for (int kt = 0; kt < 8; ++kt) {
    __syncthreads();
    gload16(gAh + kt * 32, lAh);
    gload16(gAl + kt * 32, lAl);
    gload16(gBh + kt * 32, lBh);
    gload16(gBl + kt * 32, lBl);
    __syncthreads();
    short8 Ah = *(const short8*)&As[0][fr][fk];
    short8 Al = *(const short8*)&As[1][fr][fk];
    #pragma unroll
    for (int t = 0; t < 4; ++t) {
      short8 Bh = *(const short8*)&Bs[0][t * 16 + fn][fk];
      short8 Bl = *(const short8*)&Bs[1][t * 16 + fn][fk];
      acc[t] = __builtin_amdgcn_mfma_f32_16x16x32_bf16(Ah, Bh, acc[t], 0, 0, 0);
      acc[t] = __builtin_amdgcn_mfma_f32_16x16x32_bf16(Ah, Bl, acc[t], 0, 0, 0);
      acc[t] = __builtin_amdgcn_mfma_f32_16x16x32_bf16(Al, Bh, acc[t], 0, 0, 0);
    }
  }
  float* Cc = Cp + (size_t)blockIdx.z * NN;
  int orow = x0 + w * 16 + (lane >> 4) * 4;
  int ocol = m0 + fn;
  #pragma unroll
  for (int t = 0; t < 4; ++t)
    #pragma unroll
    for (int r = 0; r < 4; ++r)
      Cc[(size_t)(orow + r) * N + ocol + t * 16] = acc[t][r];
}

// ---------------- kernel 4: reduce split-K + partial column max ----------
__global__ __launch_bounds__(1024) void k_rednorm(
    const float* __restrict__ Cp, float* __restrict__ C,
    float* __restrict__ normp) {
  int m = threadIdx.x;
  int xg = blockIdx.x;    // 0..255, 4 rows each
  float mx = -INFINITY;
  #pragma unroll
  for (int j = 0; j < 4; ++j) {
    size_t idx = (size_t)(xg * 4 + j) * N + m;
    float s = Cp[idx] + Cp[idx + NN] + Cp[idx + 2 * NN] + Cp[idx + 3 * NN];
    C[idx] = s;
    mx = fmaxf(mx, s);
  }
  normp[(size_t)xg * N + m] = mx;
}

// ---------------- kernel 5: finish norm ----------------------------------
__global__ __launch_bounds__(256) void k_norm2(
    const float* __restrict__ normp, float* __restrict__ norm) {
  int m = blockIdx.x * 256 + threadIdx.x;
  float mx = -INFINITY;
  #pragma unroll 8
  for (int xg = 0; xg < 256; ++xg)
    mx = fmaxf(mx, normp[(size_t)xg * N + m]);
  norm[m] = (mx <= 1.f) ? 1.f : mx;
}

// ---------------- kernel 6: blend + write output -------------------------
__global__ __launch_bounds__(256) void k_blend(
    const float* __restrict__ C, const float* __restrict__ norm,
    const float* __restrict__ att_stack, const float* __restrict__ ptr,
    float* __restrict__ out) {
  int gid = blockIdx.x * 256 + threadIdx.x;   // x*N + m
  int m = gid & (N - 1);
  float a = C[gid] / norm[m];
  const float4* s = (const float4*)(att_stack + (size_t)gid * L);
  float4 s0 = s[0], s1 = s[1];
  float p0 = ptr[0], p1 = ptr[1], p2 = ptr[2], p3 = ptr[3];
  float p4 = ptr[4], p5 = ptr[5], p6 = ptr[6], p7 = ptr[7];
  float4 o0, o1;
  o0.x = a * p0 + s0.x * (1.f - p0);
  o0.y = a * p1 + s0.y * (1.f - p1);
  o0.z = a * p2 + s0.z * (1.f - p2);
  o0.w = a * p3 + s0.w * (1.f - p3);
  o1.x = a * p4 + s1.x * (1.f - p4);
  o1.y = a * p5 + s1.y * (1.f - p5);
  o1.z = a * p6 + s1.z * (1.f - p6);
  o1.w = a * p7 + s1.w * (1.f - p7);
  float4* o = (float4*)(out + (size_t)gid * L);
  o[0] = o0;
  o[1] = o1;
}

extern "C" void kernel_launch(void* const* d_in, const int* in_sizes, int n_in,
                              void* d_out, int out_size, void* d_ws, size_t ws_size,
                              hipStream_t stream) {
  const float* feat      = (const float*)d_in[1];
  const float* feat_edge = (const float*)d_in[2];
  const float* c_i       = (const float*)d_in[3];
  const float* att_stack = (const float*)d_in[5];
  const float* stack_ptr = (const float*)d_in[6];
  const float* mono_mask = (const float*)d_in[8];
  const float* cross_mask= (const float*)d_in[9];
  const float* w_c       = (const float*)d_in[10];
  const float* b_c       = (const float*)d_in[11];

  float* out = (float*)d_out;

  // ws layout: 4 ushort planes (8 MB) then fp32 arrays (~22 MB)
  ushort* wv_h = (ushort*)d_ws;
  ushort* wv_l = wv_h + NN;
  ushort* Pt_h = wv_l + NN;
  ushort* Pt_l = Pt_h + NN;
  float*  Cp   = (float*)(Pt_l + NN);
  float*  C    = Cp + 4 * NN;
  float*  normp= C + NN;               // 256*N
  float*  norm = normp + (size_t)256 * N;

  float* out_tail = out + NN * L;      // stack_ptr + mem zeros

  k_wv<<<32768, 256, 0, stream>>>(feat, feat_edge, mono_mask, cross_mask,
                                  c_i, w_c, b_c, wv_h, wv_l);
  k_P<<<257, 256, 0, stream>>>(att_stack, stack_ptr, Pt_h, Pt_l, out_tail);
  dim3 mmgrid(16, 16, 4);
  k_mm<<<mmgrid, 256, 0, stream>>>(Pt_h, Pt_l, wv_h, wv_l, Cp);
  k_rednorm<<<256, 1024, 0, stream>>>(Cp, C, normp);
  k_norm2<<<4, 256, 0, stream>>>(normp, norm);
  k_blend<<<4096, 256, 0, stream>>>(C, norm, att_stack, stack_ptr, out);
}

// Round 6
// 291.095 us; speedup vs baseline: 1.2056x; 1.1047x over previous
//
#include <hip/hip_runtime.h>
#include <math.h>

#define N 1024
#define E 32
#define L 8
#define NN ((size_t)N * N)

using short8 = __attribute__((ext_vector_type(8))) short;
using f32x4v = __attribute__((ext_vector_type(4))) float;

// split fp32 into bf16 hi + bf16 lo (truncation; residual ~2^-16 relative)
__device__ inline ushort2 split_bf16(float v) {
  unsigned ui = __float_as_uint(v);
  ushort h = (ushort)(ui >> 16);
  float hv = __uint_as_float((unsigned)h << 16);
  float r = v - hv;
  ushort l = (ushort)(__float_as_uint(r) >> 16);
  return make_ushort2(h, l);
}

// async global->LDS, 16B per lane; lds dest = wave-uniform base + lane*16
__device__ inline void gload16(const void* g, void* l) {
  __builtin_amdgcn_global_load_lds(
      (const __attribute__((address_space(1))) unsigned int*)g,
      (__attribute__((address_space(3))) unsigned int*)l, 16, 0, 0);
}

// ---------------- kernel 1: wv (coalesced, 8 lanes/row, 4 rows/thread) ---
// wv[m,y] = mono[m,y] * sum_e cm[e]*(-(I-fe)^2 + relu(I+fe))
// Block = 256 threads; 4 iterations x 32 rows = 128 rows/block; 8192 blocks.
// Blocks 0..7 are exactly the m==0 rows (block-uniform query branch).
__global__ __launch_bounds__(256) void k_wv(
    const float* __restrict__ feat, const float* __restrict__ fe,
    const float* __restrict__ mono, const float* __restrict__ cm,
    const float* __restrict__ c_i, const float* __restrict__ w_c,
    const float* __restrict__ b_c,
    ushort* __restrict__ wv_h, ushort* __restrict__ wv_l) {
  __shared__ __align__(16) float qsm[32];
  int tid = threadIdx.x;
  int b = blockIdx.x;
  int seg = tid & 7;
  int rl = tid >> 3;             // 0..31 local row
  bool qblock = (b < 8);         // gid < 1024 <=> m == 0
  if (qblock) {                  // compute query cooperatively
    int e = tid >> 3, r = tid & 7;
    float s = 0.f;
    for (int h = r; h < N; h += 8) s += c_i[h] * w_c[e * N + h];
    s += __shfl_down(s, 4, 8);
    s += __shfl_down(s, 2, 8);
    s += __shfl_down(s, 1, 8);
    if (r == 0) qsm[e] = s + b_c[e];
    __syncthreads();
  }
  float4 c = *(const float4*)(cm + seg * 4);
  float4 qa;
  if (qblock) qa = *((const float4*)qsm + seg);
  #pragma unroll
  for (int it = 0; it < 4; ++it) {
    int gid = b * 128 + it * 32 + rl;   // m*N + y
    int m = gid >> 10;
    int y = gid & (N - 1);
    float4 a;
    if (qblock) {
      a = qa;
    } else {
      a = *(const float4*)(feat + ((size_t)(m - 1) * N + y) * E + seg * 4);
    }
    float4 f = *(const float4*)(fe + (size_t)y * E + seg * 4);
    float dx = a.x - f.x, dy = a.y - f.y, dz = a.z - f.z, dw = a.w - f.w;
    float s = c.x * (fmaxf(a.x + f.x, 0.f) - dx * dx)
            + c.y * (fmaxf(a.y + f.y, 0.f) - dy * dy)
            + c.z * (fmaxf(a.z + f.z, 0.f) - dz * dz)
            + c.w * (fmaxf(a.w + f.w, 0.f) - dw * dw);
    s += __shfl_down(s, 4, 8);
    s += __shfl_down(s, 2, 8);
    s += __shfl_down(s, 1, 8);
    if (seg == 0) {
      float v = mono[gid] * s;
      ushort2 hl = split_bf16(v);
      wv_h[gid] = hl.x;
      wv_l[gid] = hl.y;
    }
  }
}

// ---------------- kernel 2: P-transpose (hi/lo) + output tail ------------
// blocks [0,256): P[j,i] = att_stack[j,i,:].ptr, stored transposed Pt[i][j]
// block 256: out tail = stack_ptr + zeros
__global__ __launch_bounds__(256) void k_P(
    const float* __restrict__ att_stack, const float* __restrict__ ptr,
    ushort* __restrict__ Pt_h, ushort* __restrict__ Pt_l,
    float* __restrict__ out_tail) {
  __shared__ ushort Ts[2][64][66];   // pad 66: conflict-free column writes
  int tid = threadIdx.x;
  int b = blockIdx.x;
  if (b < 256) {
    int j0 = (b >> 4) * 64;          // k-dim of Pt
    int i0 = (b & 15) * 64;          // x-dim of Pt
    float p0 = ptr[0], p1 = ptr[1], p2 = ptr[2], p3 = ptr[3];
    float p4 = ptr[4], p5 = ptr[5], p6 = ptr[6], p7 = ptr[7];
    int w = tid >> 6, lane = tid & 63;
    #pragma unroll 4
    for (int r = 0; r < 16; ++r) {
      int jl = r * 4 + w;
      int il = lane;
      const float4* a =
          (const float4*)(att_stack + ((size_t)(j0 + jl) * N + i0 + il) * L);
      float4 a0 = a[0], a1 = a[1];
      float s = a0.x * p0 + a0.y * p1 + a0.z * p2 + a0.w * p3
              + a1.x * p4 + a1.y * p5 + a1.z * p6 + a1.w * p7;
      ushort2 hl = split_bf16(s);
      Ts[0][il][jl] = hl.x;
      Ts[1][il][jl] = hl.y;
    }
    __syncthreads();
    int il = tid >> 2, cc = tid & 3;
    size_t o = (size_t)(i0 + il) * N + j0 + cc * 16;
    {
      const uint* sp = (const uint*)&Ts[0][il][cc * 16];
      uint4 d0 = {sp[0], sp[1], sp[2], sp[3]};
      uint4 d1 = {sp[4], sp[5], sp[6], sp[7]};
      *(uint4*)&Pt_h[o] = d0;
      *(uint4*)&Pt_h[o + 8] = d1;
    }
    {
      const uint* sp = (const uint*)&Ts[1][il][cc * 16];
      uint4 d0 = {sp[0], sp[1], sp[2], sp[3]};
      uint4 d1 = {sp[4], sp[5], sp[6], sp[7]};
      *(uint4*)&Pt_l[o] = d0;
      *(uint4*)&Pt_l[o + 8] = d1;
    }
  } else {
    if (tid < 8) out_tail[tid] = ptr[tid];
    for (int i = tid; i < N; i += 256) out_tail[8 + i] = 0.f;
  }
}

// ---------------- kernel 3: MFMA matmul, full K, fused column-max --------
// C[x,m] = sum_k Pt[x][k] * wv[m][k], bf16 hi/lo (3 products).
// 64x64 tile, BK=32, K=1024; grid (16,16) = 256 blocks.
// Also emits normp[bx][m] = max over this tile's 64 x-rows.
__global__ __launch_bounds__(256) void k_mm(
    const ushort* __restrict__ Pt_h, const ushort* __restrict__ Pt_l,
    const ushort* __restrict__ wv_h, const ushort* __restrict__ wv_l,
    float* __restrict__ C, float* __restrict__ normp) {
  __shared__ ushort As[2][64][32];
  __shared__ ushort Bs[2][64][32];
  __shared__ float nm[64][17];
  int tid = threadIdx.x;
  int lane = tid & 63, w = tid >> 6;
  int x0 = blockIdx.x * 64, m0 = blockIdx.y * 64;
  int srow = w * 16 + (lane >> 2);
  int scol = (lane & 3) * 8;   // halves
  const ushort* gAh = Pt_h + (size_t)(x0 + srow) * N + scol;
  const ushort* gAl = Pt_l + (size_t)(x0 + srow) * N + scol;
  const ushort* gBh = wv_h + (size_t)(m0 + srow) * N + scol;
  const ushort* gBl = wv_l + (size_t)(m0 + srow) * N + scol;
  ushort* lAh = &As[0][w * 16][0];
  ushort* lAl = &As[1][w * 16][0];
  ushort* lBh = &Bs[0][w * 16][0];
  ushort* lBl = &Bs[1][w * 16][0];
  int fr = w * 16 + (lane & 15);
  int fk = (lane >> 4) * 8;
  int fn = lane & 15;
  f32x4v acc[4];
  #pragma unroll
  for (int t = 0; t < 4; ++t) acc[t] = (f32x4v){0.f, 0.f, 0.f, 0.f};
  for (int kt = 0; kt < 32; ++kt) {
    __syncthreads();
    gload16(gAh + kt * 32, lAh);
    gload16(gAl + kt * 32, lAl);
    gload16(gBh + kt * 32, lBh);
    gload16(gBl + kt * 32, lBl);
    __syncthreads();
    short8 Ah = *(const short8*)&As[0][fr][fk];
    short8 Al = *(const short8*)&As[1][fr][fk];
    #pragma unroll
    for (int t = 0; t < 4; ++t) {
      short8 Bh = *(const short8*)&Bs[0][t * 16 + fn][fk];
      short8 Bl = *(const short8*)&Bs[1][t * 16 + fn][fk];
      acc[t] = __builtin_amdgcn_mfma_f32_16x16x32_bf16(Ah, Bh, acc[t], 0, 0, 0);
      acc[t] = __builtin_amdgcn_mfma_f32_16x16x32_bf16(Ah, Bl, acc[t], 0, 0, 0);
      acc[t] = __builtin_amdgcn_mfma_f32_16x16x32_bf16(Al, Bh, acc[t], 0, 0, 0);
    }
  }
  // C/D layout: col = lane&15, row = (lane>>4)*4 + reg  [m89-verified]
  int orow = x0 + w * 16 + (lane >> 4) * 4;
  int ocol = m0 + fn;
  int cidx = w * 4 + (lane >> 4);    // 16 contributors per m-column
  #pragma unroll
  for (int t = 0; t < 4; ++t) {
    float mx = -INFINITY;
    #pragma unroll
    for (int r = 0; r < 4; ++r) {
      float v = acc[t][r];
      C[(size_t)(orow + r) * N + ocol + t * 16] = v;
      mx = fmaxf(mx, v);
    }
    nm[t * 16 + fn][cidx] = mx;
  }
  __syncthreads();
  if (tid < 64) {
    float mx = nm[tid][0];
    #pragma unroll
    for (int j = 1; j < 16; ++j) mx = fmaxf(mx, nm[tid][j]);
    normp[(size_t)blockIdx.x * N + m0 + tid] = mx;
  }
}

// ---------------- kernel 4: finish norm (max over 16 x-tiles) ------------
__global__ __launch_bounds__(256) void k_norm2(
    const float* __restrict__ normp, float* __restrict__ norm) {
  int m = blockIdx.x * 256 + threadIdx.x;
  float mx = normp[m];
  #pragma unroll
  for (int xg = 1; xg < 16; ++xg)
    mx = fmaxf(mx, normp[(size_t)xg * N + m]);
  norm[m] = (mx <= 1.f) ? 1.f : mx;
}

// ---------------- kernel 5: blend + write output -------------------------
__global__ __launch_bounds__(256) void k_blend(
    const float* __restrict__ C, const float* __restrict__ norm,
    const float* __restrict__ att_stack, const float* __restrict__ ptr,
    float* __restrict__ out) {
  int gid = blockIdx.x * 256 + threadIdx.x;   // x*N + m
  int m = gid & (N - 1);
  float a = C[gid] / norm[m];
  const float4* s = (const float4*)(att_stack + (size_t)gid * L);
  float4 s0 = s[0], s1 = s[1];
  float p0 = ptr[0], p1 = ptr[1], p2 = ptr[2], p3 = ptr[3];
  float p4 = ptr[4], p5 = ptr[5], p6 = ptr[6], p7 = ptr[7];
  float4 o0, o1;
  o0.x = a * p0 + s0.x * (1.f - p0);
  o0.y = a * p1 + s0.y * (1.f - p1);
  o0.z = a * p2 + s0.z * (1.f - p2);
  o0.w = a * p3 + s0.w * (1.f - p3);
  o1.x = a * p4 + s1.x * (1.f - p4);
  o1.y = a * p5 + s1.y * (1.f - p5);
  o1.z = a * p6 + s1.z * (1.f - p6);
  o1.w = a * p7 + s1.w * (1.f - p7);
  float4* o = (float4*)(out + (size_t)gid * L);
  o[0] = o0;
  o[1] = o1;
}

extern "C" void kernel_launch(void* const* d_in, const int* in_sizes, int n_in,
                              void* d_out, int out_size, void* d_ws, size_t ws_size,
                              hipStream_t stream) {
  const float* feat      = (const float*)d_in[1];
  const float* feat_edge = (const float*)d_in[2];
  const float* c_i       = (const float*)d_in[3];
  const float* att_stack = (const float*)d_in[5];
  const float* stack_ptr = (const float*)d_in[6];
  const float* mono_mask = (const float*)d_in[8];
  const float* cross_mask= (const float*)d_in[9];
  const float* w_c       = (const float*)d_in[10];
  const float* b_c       = (const float*)d_in[11];

  float* out = (float*)d_out;

  // ws layout: 4 ushort planes (8 MB), C (4 MB), normp (64 KB), norm (4 KB)
  ushort* wv_h = (ushort*)d_ws;
  ushort* wv_l = wv_h + NN;
  ushort* Pt_h = wv_l + NN;
  ushort* Pt_l = Pt_h + NN;
  float*  C    = (float*)(Pt_l + NN);
  float*  normp= C + NN;               // 16*N
  float*  norm = normp + (size_t)16 * N;

  float* out_tail = out + NN * L;      // stack_ptr + mem zeros

  k_wv<<<8192, 256, 0, stream>>>(feat, feat_edge, mono_mask, cross_mask,
                                 c_i, w_c, b_c, wv_h, wv_l);
  k_P<<<257, 256, 0, stream>>>(att_stack, stack_ptr, Pt_h, Pt_l, out_tail);
  dim3 mmgrid(16, 16);
  k_mm<<<mmgrid, 256, 0, stream>>>(Pt_h, Pt_l, wv_h, wv_l, C, normp);
  k_norm2<<<4, 256, 0, stream>>>(normp, norm);
  k_blend<<<4096, 256, 0, stream>>>(C, norm, att_stack, stack_ptr, out);
}